// Round 8
// baseline (126.726 us; speedup 1.0000x reference)
//
#include <hip/hip_runtime.h>
#include <math.h>

#define NPTS 8192
#define KNN 32

typedef unsigned int uint;
typedef unsigned long long u64;
typedef float v2f __attribute__((ext_vector_type(2)));

#if __has_builtin(__builtin_elementwise_fma)
__device__ __forceinline__ v2f fma2(v2f a, v2f b, v2f c) {
    return __builtin_elementwise_fma(a, b, c);
}
#else
__device__ __forceinline__ v2f fma2(v2f a, v2f b, v2f c) {
    v2f r; r.x = fmaf(a.x, b.x, c.x); r.y = fmaf(a.y, b.y, c.y); return r;
}
#endif
__device__ __forceinline__ v2f mk2(float a, float b) { v2f r; r.x = a; r.y = b; return r; }

// ---- workspace layout (bytes) ----
#define OFF_PTS4   0                    // float4[N]            131072
#define OFF_WC     131072               // float[128*32]        16384
#define OFF_BC     147456               // float[128]           512
#define OFF_WQ     147968               // float[128*3]         1536  (Wf_pc@Wpc)
#define OFF_BQ     149504               // float[128]           512   (Wf_pc@bpc+bf)
#define OFF_G      150016               // float[N*128]         4194304
#define OFF_F      5392896              // float[N*128]         4194304
#define OFF_CELLID 9587200              // uint[N]              32768
#define OFF_SPTS   9619968              // float4[N] cell-sorted 131072
#define OFF_SIDX   9751040              // uint[N] orig index   32768
#define OFF_CSTART 9783808              // uint[4097]           16388

// 16^3 grid over [-6,6]^3, cell size 0.75, x fastest
__device__ __forceinline__ int cellco(float x) {
    int c = (int)floorf((x + 6.0f) * 1.3333334f);
    return min(15, max(0, c));
}

__device__ __forceinline__ uint fkey(float d) {
    uint bits = __float_as_uint(d);
    return bits ^ (0x80000000u | (uint)((int)bits >> 31));  // monotone sortable
}
__device__ __forceinline__ float finv(uint key) {
    uint bits = (key & 0x80000000u) ? (key ^ 0x80000000u) : ~key;
    return __uint_as_float(bits);
}
__device__ __forceinline__ uint mbcnt64(u64 m) {
    uint lo = __builtin_amdgcn_mbcnt_lo((uint)m, 0u);
    return __builtin_amdgcn_mbcnt_hi((uint)(m >> 32), lo);
}

// ---------------------------------------------------------------------------
// Fused preprocessing: blocks 0..31 build pts4 + cellid; 32..50 Wc/bc;
// block 51 builds Wq = Wf[:,128:]@(Wp2@Wp1), bq = Wf[:,128:]@(Wp2@bp1+bp2)+bf.
__launch_bounds__(256)
__global__ void k_prep_combine(const float* __restrict__ cloud, float4* __restrict__ pts4,
                               uint* __restrict__ cellid,
                               const float* __restrict__ W1, const float* __restrict__ b1,
                               const float* __restrict__ W2, const float* __restrict__ b2,
                               const float* __restrict__ Wp1, const float* __restrict__ bp1,
                               const float* __restrict__ Wp2, const float* __restrict__ bp2,
                               const float* __restrict__ Wf, const float* __restrict__ bf,
                               float* __restrict__ Wc, float* __restrict__ bc,
                               float* __restrict__ Wq, float* __restrict__ bq) {
    int bid = blockIdx.x;
    int t = threadIdx.x;
    if (bid < 32) {
        int n = bid * 256 + t;
        float x = cloud[n * 3 + 0], y = cloud[n * 3 + 1], z = cloud[n * 3 + 2];
        float sq = fmaf(x, x, fmaf(y, y, z * z));
        pts4[n] = make_float4(x, y, z, sq);
        cellid[n] = (uint)((cellco(z) * 16 + cellco(y)) * 16 + cellco(x));
        return;
    }
    if (bid == 51) {
        __shared__ float wpcS[384];
        __shared__ float bpcS[128];
        for (int i = t; i < 384; i += 256) {
            int o = i / 3, c = i - o * 3;
            float a = 0.f;
            for (int u = 0; u < 64; ++u) a = fmaf(Wp2[o * 64 + u], Wp1[u * 3 + c], a);
            wpcS[i] = a;
        }
        if (t < 128) {
            float a = bp2[t];
            for (int u = 0; u < 64; ++u) a = fmaf(Wp2[t * 64 + u], bp1[u], a);
            bpcS[t] = a;
        }
        __syncthreads();
        for (int i = t; i < 384; i += 256) {
            int d = i / 3, c = i - d * 3;
            float a = 0.f;
            for (int o = 0; o < 128; ++o) a = fmaf(Wf[d * 256 + 128 + o], wpcS[o * 3 + c], a);
            Wq[i] = a;
        }
        if (t < 128) {
            float a = bf[t];
            for (int o = 0; o < 128; ++o) a = fmaf(Wf[t * 256 + 128 + o], bpcS[o], a);
            bq[t] = a;
        }
        return;
    }
    int id = (bid - 32) * 256 + t;
    if (id < 4096) {                 // Wc[d][c] = sum_o W2[d][o] W1[o][c]
        int d = id >> 5, c = id & 31;
        float a0 = 0.f, a1 = 0.f;
        for (int o = 0; o < 64; o += 2) {
            a0 = fmaf(W2[d * 64 + o], W1[o * 32 + c], a0);
            a1 = fmaf(W2[d * 64 + o + 1], W1[(o + 1) * 32 + c], a1);
        }
        Wc[id] = a0 + a1;
    } else if (id < 4224) {          // bc[d]
        int d = id - 4096;
        float a = b2[d];
        for (int o = 0; o < 64; ++o) a = fmaf(W2[d * 64 + o], b1[o], a);
        bc[d] = a;
    }
}

// ---------------------------------------------------------------------------
// Deterministic cell sort: one WAVE per cell (1024 blocks x 4 waves = 4096).
// Each wave scans all 8192 cellids in index order; counts cells < own and
// ballot-compacts its own members (index-ordered) into LDS, then writes the
// contiguous CSR segment. No atomics -> deterministic.
#define OWNCAP 320
__launch_bounds__(256)
__global__ void k_cellsort(const uint* __restrict__ cellid, const float4* __restrict__ pts4,
                           float4* __restrict__ sPts, uint* __restrict__ sIdx,
                           uint* __restrict__ cellStart) {
    __shared__ uint ownb[4][OWNCAP];
    int t = threadIdx.x, w = t >> 6, lane = t & 63;
    uint c = blockIdx.x * 4u + (uint)w;
    uint nless = 0, nown = 0;
    for (int it = 0; it < 128; ++it) {
        uint i = (uint)(it << 6) + (uint)lane;
        uint ci = cellid[i];
        nless += (uint)__popcll(__ballot(ci < c));
        bool own = (ci == c);
        u64 m = __ballot(own);
        if (m) {
            uint pos = nown + mbcnt64(m);
            if (own && pos < OWNCAP) ownb[w][pos] = i;
            nown += (uint)__popcll(m);
        }
    }
    if (nown > OWNCAP) nown = OWNCAP;
    if (lane == 0) {
        cellStart[c] = nless;
        if (c == 4095u) cellStart[4096] = nless + nown;
    }
    for (uint k = lane; k < nown; k += 64) {
        uint oi = ownb[w][k];
        sPts[nless + k] = pts4[oi];
        sIdx[nless + k] = oi;
    }
}

// ---------------------------------------------------------------------------
// g[n][d] = sum_c Wc[d][c]*feats[n][c] + bc[d].  32 points/block, 256 blocks.
__launch_bounds__(256)
__global__ void k_gfeat(const float* __restrict__ img_feat, const float* __restrict__ Wc,
                        const float* __restrict__ bc, float* __restrict__ g) {
    __shared__ float wcs[128 * 36];
    __shared__ float ftT[32][36];
    __shared__ float bcs[128];
    int t = threadIdx.x;
    int n0 = blockIdx.x * 32;

    for (int i = t; i < 1024; i += 256) {
        float4 v = ((const float4*)Wc)[i];
        int d = i >> 3, c = (i & 7) * 4;
        wcs[d * 36 + c + 0] = v.x; wcs[d * 36 + c + 1] = v.y;
        wcs[d * 36 + c + 2] = v.z; wcs[d * 36 + c + 3] = v.w;
    }
    if (t < 128) bcs[t] = bc[t];
    {
        int c = t >> 3, ng = (t & 7) * 4;
        float4 v = *(const float4*)&img_feat[c * NPTS + n0 + ng];
        ftT[ng + 0][c] = v.x; ftT[ng + 1][c] = v.y;
        ftT[ng + 2][c] = v.z; ftT[ng + 3][c] = v.w;
    }
    __syncthreads();

    int d = t & 127, half = t >> 7;
    v2f wr2[16];
#pragma unroll
    for (int c4 = 0; c4 < 8; ++c4) {
        float4 wv = *(const float4*)&wcs[d * 36 + c4 * 4];
        wr2[2 * c4 + 0] = mk2(wv.x, wv.y);
        wr2[2 * c4 + 1] = mk2(wv.z, wv.w);
    }
    float bb = bcs[d];
    for (int nl = half * 16; nl < half * 16 + 16; ++nl) {
        v2f acc = mk2(bb, 0.f);
#pragma unroll
        for (int c4 = 0; c4 < 8; ++c4) {
            float4 fv = *(const float4*)&ftT[nl][c4 * 4];
            acc = fma2(wr2[2 * c4 + 0], mk2(fv.x, fv.y), acc);
            acc = fma2(wr2[2 * c4 + 1], mk2(fv.z, fv.w), acc);
        }
        g[(n0 + nl) * 128 + d] = acc.x + acc.y;
    }
}

// ---------------------------------------------------------------------------
// Exact KNN + fused surround branch, grid-pruned.
// 4 independent waves / block, one query each. No barriers.
#define SPCAP 384
__launch_bounds__(256)
__global__ void k_knn(const float4* __restrict__ pts4, const float4* __restrict__ sPts,
                      const uint* __restrict__ sIdx, const uint* __restrict__ cellStart,
                      const float* __restrict__ g, float* __restrict__ F) {
    __shared__ uint spill[4][SPCAP];          // 6 KB
    __shared__ uint2 selEJ[4][32];            // (.x = e bits, .y = orig idx)

    int t = threadIdx.x, w = t >> 6, lane = t & 63;
    int q = blockIdx.x * 4 + w;
    float4 qq = pts4[q];
    float m2x = -2.f * qq.x, m2y = -2.f * qq.y, m2z = -2.f * qq.z, qw4 = qq.w;

    // ---- prepass: per-lane min over samples 0..2047 (original order = random) ----
    float mn = 3.4e38f;
    {
        float4 pp = pts4[lane];
        for (int s = 0; s < 32; ++s) {
            float4 pnx;
            if (s < 31) pnx = pts4[lane + ((s + 1) << 6)];
            float d2 = fmaf(m2x, pp.x, fmaf(m2y, pp.y, fmaf(m2z, pp.z, qw4 + pp.w)));
            mn = fminf(mn, d2);
            pp = pnx;
        }
    }
    // exact 32nd-smallest of the 64 lane minima (bit-radix on ballots)
    float T0;
    {
        uint kmn = fkey(mn);
        uint P = 0x80000000u;
        for (int b = 30; b >= 0; --b) {
            uint cand = P | (1u << b);
            if ((uint)__popcll(__ballot(kmn < cand)) < 32u) P = cand;
        }
        T0 = finv(P);
    }

    // ---- cell cover of the T0-ball (provable superset of {d2<=T0}) ----
    float r = sqrtf(fmaxf(T0, 0.0f) + 1e-4f);
    int cx0 = cellco(qq.x - r), cx1 = cellco(qq.x + r);
    int cy0 = cellco(qq.y - r), cy1 = cellco(qq.y + r);
    int cz0 = cellco(qq.z - r), cz1 = cellco(qq.z + r);

    // ---- sweep covered rows; spill positions with d2 <= T0 ----
    uint scnt = 0;
    for (int cz = cz0; cz <= cz1; ++cz) {
        for (int cy = cy0; cy <= cy1; ++cy) {
            int c0 = (cz * 16 + cy) * 16;
            uint s0 = cellStart[c0 + cx0];
            uint s1 = cellStart[c0 + cx1 + 1];
            for (uint base = s0; base < s1; base += 64) {
                uint i = base + (uint)lane;
                bool v = i < s1;
                uint isafe = v ? i : 8191u;
                float4 p = sPts[isafe];
                float d2 = fmaf(m2x, p.x, fmaf(m2y, p.y, fmaf(m2z, p.z, qw4 + p.w)));
                bool in_ = v && (d2 <= T0);
                u64 mk = __ballot(in_);
                if (mk) {
                    uint pos = scnt + mbcnt64(mk);
                    if (in_ && pos < SPCAP) spill[w][pos] = i;
                    scnt += (uint)__popcll(mk);
                }
            }
        }
    }
    uint total = min(scnt, (uint)SPCAP);
    bool has3 = total > 192, has4 = total > 256, has5 = total > 320;

    // ---- refine: exact top-32 by (key, orig idx) via ballot radix ----
#define LOADSLOT(S, KK, ID) { \
    uint gp = (uint)(64 * (S)) + (uint)lane; \
    KK = 0xFFFFFFFFu; ID = 0xFFFFFFFFu; \
    if (gp < total) { \
        uint posi = spill[w][gp]; \
        float4 pz = sPts[posi]; \
        float d2 = fmaf(m2x, pz.x, fmaf(m2y, pz.y, fmaf(m2z, pz.z, qw4 + pz.w))); \
        KK = fkey(d2); ID = sIdx[posi]; } }

    uint kk0, kk1, kk2, kk3, kk4, kk5, id0, id1, id2, id3, id4, id5;
    LOADSLOT(0, kk0, id0)
    LOADSLOT(1, kk1, id1)
    LOADSLOT(2, kk2, id2)
    kk3 = 0xFFFFFFFFu; id3 = 0xFFFFFFFFu;
    kk4 = 0xFFFFFFFFu; id4 = 0xFFFFFFFFu;
    kk5 = 0xFFFFFFFFu; id5 = 0xFFFFFFFFu;
    if (has3) LOADSLOT(3, kk3, id3)
    if (has4) LOADSLOT(4, kk4, id4)
    if (has5) LOADSLOT(5, kk5, id5)

    uint Kc = 0x80000000u;
    for (int b = 30; b >= 0; --b) {
        uint cand = Kc | (1u << b);
        uint cnt = (uint)__popcll(__ballot(kk0 < cand))
                 + (uint)__popcll(__ballot(kk1 < cand))
                 + (uint)__popcll(__ballot(kk2 < cand));
        if (has3) cnt += (uint)__popcll(__ballot(kk3 < cand));
        if (has4) cnt += (uint)__popcll(__ballot(kk4 < cand));
        if (has5) cnt += (uint)__popcll(__ballot(kk5 < cand));
        if (cnt < 32u) Kc = cand;
    }
    uint nlt = (uint)__popcll(__ballot(kk0 < Kc)) + (uint)__popcll(__ballot(kk1 < Kc))
             + (uint)__popcll(__ballot(kk2 < Kc)) + (uint)__popcll(__ballot(kk3 < Kc))
             + (uint)__popcll(__ballot(kk4 < Kc)) + (uint)__popcll(__ballot(kk5 < Kc));
    uint ntie = (uint)__popcll(__ballot(kk0 == Kc)) + (uint)__popcll(__ballot(kk1 == Kc))
              + (uint)__popcll(__ballot(kk2 == Kc)) + (uint)__popcll(__ballot(kk3 == Kc))
              + (uint)__popcll(__ballot(kk4 == Kc)) + (uint)__popcll(__ballot(kk5 == Kc));
    uint need = 32u - nlt;
    uint icut = 0xFFFFFFFFu;
    if (ntie != need) {   // tie-break by smallest orig index (unique, 13 bits)
        uint P2 = 0u;
        for (int b = 12; b >= 0; --b) {
            uint cand = P2 | (1u << b);
            uint cnt = (uint)__popcll(__ballot(kk0 == Kc && id0 < cand))
                     + (uint)__popcll(__ballot(kk1 == Kc && id1 < cand))
                     + (uint)__popcll(__ballot(kk2 == Kc && id2 < cand));
            if (has3) cnt += (uint)__popcll(__ballot(kk3 == Kc && id3 < cand));
            if (has4) cnt += (uint)__popcll(__ballot(kk4 == Kc && id4 < cand));
            if (has5) cnt += (uint)__popcll(__ballot(kk5 == Kc && id5 < cand));
            if (cnt < need) P2 = cand;
        }
        icut = P2;
    }

    uint dpos = 0;
#define WSEL(KK, ID) { bool acc = (KK < Kc) || (KK == Kc && ID <= icut); \
    u64 mk = __ballot(acc); \
    if (mk) { uint pos = dpos + mbcnt64(mk); \
        if (acc) selEJ[w][pos].y = ID; \
        dpos += (uint)__popcll(mk); } }
    WSEL(kk0, id0) WSEL(kk1, id1) WSEL(kk2, id2)
    WSEL(kk3, id3) WSEL(kk4, id4) WSEL(kk5, id5)

    // ---- fused surround branch (same wave, own query) ----
    int k = lane & 31;
    uint j = selEJ[w][k].y;
    float4 pj = pts4[j];
    float dx = qq.x - pj.x, dy = qq.y - pj.y, dz = qq.z - pj.z;
    float dist = sqrtf(fmaf(dx, dx, fmaf(dy, dy, dz * dz)));
    float dmin = dist;
    for (int off = 16; off >= 1; off >>= 1) dmin = fminf(dmin, __shfl_xor(dmin, off));
    float e = expf(dmin - dist);
    float S = e;
    for (int off = 16; off >= 1; off >>= 1) S += __shfl_xor(S, off);
    if (lane < 32) selEJ[w][k].x = __float_as_uint(e);

    int d0 = lane * 2;
    float m0 = -INFINITY, m1 = -INFINITY;
#pragma unroll 4
    for (int kx = 0; kx < 32; ++kx) {
        uint2 ej = selEJ[w][kx];       // broadcast read
        float ek = __uint_as_float(ej.x);
        float2 gv = *(const float2*)&g[ej.y * 128u + (uint)d0];
        m0 = fmaxf(m0, ek * gv.x);
        m1 = fmaxf(m1, ek * gv.y);
    }
    float inv = 1.0f / S;
    *(float2*)&F[q * 128 + d0] = make_float2(m0 * inv, m1 * inv);
}

// ---------------------------------------------------------------------------
// out[d][n] = sum_{c<128} Wf[d][c]*F[n][c] + Wq[d]·pts[n] + bq[d]
__launch_bounds__(256)
__global__ void k_final(const float* __restrict__ F, const float* __restrict__ Wf,
                        const float* __restrict__ Wq, const float* __restrict__ bq,
                        const float4* __restrict__ pts4, float* __restrict__ out) {
    __shared__ float Fs[128 * 34];
    __shared__ float wfs[32 * 132];
    int t = threadIdx.x;
    int tn = t & 15;
    int td = t >> 4;
    int n0 = blockIdx.x * 32;
    int d0 = td * 8;

    {
        const float4* Fv = (const float4*)(F + n0 * 128);
        for (int i = t; i < 1024; i += 256) {
            float4 v = Fv[i];
            int nn = i >> 5;
            int kk = (i & 31) * 4;
            Fs[(kk + 0) * 34 + nn] = v.x; Fs[(kk + 1) * 34 + nn] = v.y;
            Fs[(kk + 2) * 34 + nn] = v.z; Fs[(kk + 3) * 34 + nn] = v.w;
        }
    }

    v2f acc2[2][4];
#pragma unroll
    for (int a = 0; a < 2; ++a)
#pragma unroll
        for (int jj = 0; jj < 4; ++jj) acc2[a][jj] = mk2(0.f, 0.f);

    for (int kc = 0; kc < 4; ++kc) {
        __syncthreads();
        for (int i = t; i < 1024; i += 256) {
            int d = i >> 3;
            int kkg = (i & 7) * 4;
            float4 v = *(const float4*)&Wf[d * 256 + kc * 32 + kkg];
            wfs[(kkg + 0) * 132 + d] = v.x; wfs[(kkg + 1) * 132 + d] = v.y;
            wfs[(kkg + 2) * 132 + d] = v.z; wfs[(kkg + 3) * 132 + d] = v.w;
        }
        __syncthreads();
#pragma unroll 4
        for (int kk = 0; kk < 32; ++kk) {
            int k = kc * 32 + kk;
            float2 f = *(const float2*)&Fs[k * 34 + tn * 2];
            const float* wr = &wfs[kk * 132 + d0];
            float4 wa = *(const float4*)wr;
            float4 wb = *(const float4*)(wr + 4);
            v2f w0 = mk2(wa.x, wa.y), w1 = mk2(wa.z, wa.w);
            v2f w2 = mk2(wb.x, wb.y), w3 = mk2(wb.z, wb.w);
            v2f fx = mk2(f.x, f.x), fy = mk2(f.y, f.y);
            acc2[0][0] = fma2(fx, w0, acc2[0][0]); acc2[1][0] = fma2(fy, w0, acc2[1][0]);
            acc2[0][1] = fma2(fx, w1, acc2[0][1]); acc2[1][1] = fma2(fy, w1, acc2[1][1]);
            acc2[0][2] = fma2(fx, w2, acc2[0][2]); acc2[1][2] = fma2(fy, w2, acc2[1][2]);
            acc2[0][3] = fma2(fx, w3, acc2[0][3]); acc2[1][3] = fma2(fy, w3, acc2[1][3]);
        }
    }

    float4 pA = pts4[n0 + tn * 2], pB = pts4[n0 + tn * 2 + 1];
#pragma unroll
    for (int jj = 0; jj < 4; ++jj) {
        int dA = d0 + 2 * jj, dB = dA + 1;
        float qa0 = Wq[dA * 3 + 0], qa1 = Wq[dA * 3 + 1], qa2 = Wq[dA * 3 + 2];
        float qb0 = Wq[dB * 3 + 0], qb1 = Wq[dB * 3 + 1], qb2 = Wq[dB * 3 + 2];
        float ba = bq[dA], bb = bq[dB];
        float oA0 = acc2[0][jj].x + fmaf(qa0, pA.x, fmaf(qa1, pA.y, fmaf(qa2, pA.z, ba)));
        float oA1 = acc2[1][jj].x + fmaf(qa0, pB.x, fmaf(qa1, pB.y, fmaf(qa2, pB.z, ba)));
        float oB0 = acc2[0][jj].y + fmaf(qb0, pA.x, fmaf(qb1, pA.y, fmaf(qb2, pA.z, bb)));
        float oB1 = acc2[1][jj].y + fmaf(qb0, pB.x, fmaf(qb1, pB.y, fmaf(qb2, pB.z, bb)));
        *(float2*)&out[dA * NPTS + n0 + tn * 2] = make_float2(oA0, oA1);
        *(float2*)&out[dB * NPTS + n0 + tn * 2] = make_float2(oB0, oB1);
    }
}

// ---------------------------------------------------------------------------
extern "C" void kernel_launch(void* const* d_in, const int* in_sizes, int n_in,
                              void* d_out, int out_size, void* d_ws, size_t ws_size,
                              hipStream_t stream) {
    const float* img_feat = (const float*)d_in[0];
    const float* cloud    = (const float*)d_in[1];
    const float* W1  = (const float*)d_in[2];
    const float* b1  = (const float*)d_in[3];
    const float* W2  = (const float*)d_in[4];
    const float* b2  = (const float*)d_in[5];
    const float* Wp1 = (const float*)d_in[6];
    const float* bp1 = (const float*)d_in[7];
    const float* Wp2 = (const float*)d_in[8];
    const float* bp2 = (const float*)d_in[9];
    const float* Wf  = (const float*)d_in[10];
    const float* bf  = (const float*)d_in[11];
    float* out = (float*)d_out;

    char* ws = (char*)d_ws;
    float4* pts4 = (float4*)(ws + OFF_PTS4);
    float* Wc  = (float*)(ws + OFF_WC);
    float* bc  = (float*)(ws + OFF_BC);
    float* Wq  = (float*)(ws + OFF_WQ);
    float* bq  = (float*)(ws + OFF_BQ);
    float* g   = (float*)(ws + OFF_G);
    float* F   = (float*)(ws + OFF_F);
    uint*  cellid = (uint*)(ws + OFF_CELLID);
    float4* sPts = (float4*)(ws + OFF_SPTS);
    uint*  sIdx = (uint*)(ws + OFF_SIDX);
    uint*  cellStart = (uint*)(ws + OFF_CSTART);

    k_prep_combine<<<52, 256, 0, stream>>>(cloud, pts4, cellid, W1, b1, W2, b2,
                                           Wp1, bp1, Wp2, bp2, Wf, bf, Wc, bc, Wq, bq);
    k_cellsort<<<1024, 256, 0, stream>>>(cellid, pts4, sPts, sIdx, cellStart);
    k_gfeat<<<NPTS / 32, 256, 0, stream>>>(img_feat, Wc, bc, g);
    k_knn<<<NPTS / 4, 256, 0, stream>>>(pts4, sPts, sIdx, cellStart, g, F);
    k_final<<<NPTS / 32, 256, 0, stream>>>(F, Wf, Wq, bq, pts4, out);
}

// Round 9
// 78.673 us; speedup vs baseline: 1.6108x; 1.6108x over previous
//
#include <hip/hip_runtime.h>
#include <math.h>

#define NPTS 8192
#define KNN 32

typedef unsigned int uint;
typedef unsigned long long u64;
typedef float v2f __attribute__((ext_vector_type(2)));

#if __has_builtin(__builtin_elementwise_fma)
__device__ __forceinline__ v2f fma2(v2f a, v2f b, v2f c) {
    return __builtin_elementwise_fma(a, b, c);
}
#else
__device__ __forceinline__ v2f fma2(v2f a, v2f b, v2f c) {
    v2f r; r.x = fmaf(a.x, b.x, c.x); r.y = fmaf(a.y, b.y, c.y); return r;
}
#endif
__device__ __forceinline__ v2f mk2(float a, float b) { v2f r; r.x = a; r.y = b; return r; }

// ---- workspace layout (bytes) ----
#define OFF_PTS4 0                      // float4[N]            131072
#define OFF_WC   131072                 // float[128*32]        16384
#define OFF_BC   147456                 // float[128]           512
#define OFF_WQ   147968                 // float[128*3]         1536  (Wf_pc@Wpc)
#define OFF_BQ   149504                 // float[128]           512   (Wf_pc@bpc+bf)
#define OFF_G    150016                 // float[N*128]         4194304
#define OFF_F    5392896                // float[N*128] row-major sur only 4194304

__device__ __forceinline__ uint fkey(float d) {
    uint bits = __float_as_uint(d);
    return bits ^ (0x80000000u | (uint)((int)bits >> 31));  // monotone sortable
}
__device__ __forceinline__ float finv(uint key) {
    uint bits = (key & 0x80000000u) ? (key ^ 0x80000000u) : ~key;
    return __uint_as_float(bits);
}
__device__ __forceinline__ uint mbcnt64(u64 m) {
    uint lo = __builtin_amdgcn_mbcnt_lo((uint)m, 0u);
    return __builtin_amdgcn_mbcnt_hi((uint)(m >> 32), lo);
}

// ---------------------------------------------------------------------------
// Fused preprocessing: blocks 0..31 build pts4; blocks 32..50 build Wc/bc;
// block 51 builds Wq = Wf[:,128:]@(Wp2@Wp1), bq = Wf[:,128:]@(Wp2@bp1+bp2)+bf.
__launch_bounds__(256)
__global__ void k_prep_combine(const float* __restrict__ cloud, float4* __restrict__ pts4,
                               const float* __restrict__ W1, const float* __restrict__ b1,
                               const float* __restrict__ W2, const float* __restrict__ b2,
                               const float* __restrict__ Wp1, const float* __restrict__ bp1,
                               const float* __restrict__ Wp2, const float* __restrict__ bp2,
                               const float* __restrict__ Wf, const float* __restrict__ bf,
                               float* __restrict__ Wc, float* __restrict__ bc,
                               float* __restrict__ Wq, float* __restrict__ bq) {
    int bid = blockIdx.x;
    int t = threadIdx.x;
    if (bid < 32) {
        int n = bid * 256 + t;
        float x = cloud[n * 3 + 0], y = cloud[n * 3 + 1], z = cloud[n * 3 + 2];
        float sq = fmaf(x, x, fmaf(y, y, z * z));
        pts4[n] = make_float4(x, y, z, sq);
        return;
    }
    if (bid == 51) {
        __shared__ float wpcS[384];
        __shared__ float bpcS[128];
        for (int i = t; i < 384; i += 256) {
            int o = i / 3, c = i - o * 3;
            float a = 0.f;
            for (int u = 0; u < 64; ++u) a = fmaf(Wp2[o * 64 + u], Wp1[u * 3 + c], a);
            wpcS[i] = a;
        }
        if (t < 128) {
            float a = bp2[t];
            for (int u = 0; u < 64; ++u) a = fmaf(Wp2[t * 64 + u], bp1[u], a);
            bpcS[t] = a;
        }
        __syncthreads();
        for (int i = t; i < 384; i += 256) {
            int d = i / 3, c = i - d * 3;
            float a = 0.f;
            for (int o = 0; o < 128; ++o) a = fmaf(Wf[d * 256 + 128 + o], wpcS[o * 3 + c], a);
            Wq[i] = a;
        }
        if (t < 128) {
            float a = bf[t];
            for (int o = 0; o < 128; ++o) a = fmaf(Wf[t * 256 + 128 + o], bpcS[o], a);
            bq[t] = a;
        }
        return;
    }
    int id = (bid - 32) * 256 + t;
    if (id < 4096) {                 // Wc[d][c] = sum_o W2[d][o] W1[o][c]
        int d = id >> 5, c = id & 31;
        float a0 = 0.f, a1 = 0.f;
        for (int o = 0; o < 64; o += 2) {
            a0 = fmaf(W2[d * 64 + o], W1[o * 32 + c], a0);
            a1 = fmaf(W2[d * 64 + o + 1], W1[(o + 1) * 32 + c], a1);
        }
        Wc[id] = a0 + a1;
    } else if (id < 4224) {          // bc[d]
        int d = id - 4096;
        float a = b2[d];
        for (int o = 0; o < 64; ++o) a = fmaf(W2[d * 64 + o], b1[o], a);
        bc[d] = a;
    }
}

// ---------------------------------------------------------------------------
// g[n][d] = sum_c Wc[d][c]*feats[n][c] + bc[d].
// 8 points/block, 1024 blocks (4 blocks/CU -> 16 waves/CU). Wc row in regs
// (16 KB, L2-hot); only the img_feat transpose tile in LDS.
__launch_bounds__(256)
__global__ void k_gfeat(const float* __restrict__ img_feat, const float* __restrict__ Wc,
                        const float* __restrict__ bc, float* __restrict__ g) {
    __shared__ float ftT[8][36];      // [n][c]
    int t = threadIdx.x;
    int n0 = blockIdx.x * 8;

    if (t < 64) {                     // 32c x 8n: one float4 per thread
        int c = t >> 1, ng = (t & 1) * 4;
        float4 v = *(const float4*)&img_feat[c * NPTS + n0 + ng];
        ftT[ng + 0][c] = v.x; ftT[ng + 1][c] = v.y;
        ftT[ng + 2][c] = v.z; ftT[ng + 3][c] = v.w;
    }

    int d = t & 127, half = t >> 7;
    v2f wr2[16];
#pragma unroll
    for (int c4 = 0; c4 < 8; ++c4) {
        float4 wv = *(const float4*)&Wc[d * 32 + c4 * 4];
        wr2[2 * c4 + 0] = mk2(wv.x, wv.y);
        wr2[2 * c4 + 1] = mk2(wv.z, wv.w);
    }
    float bb = bc[d];
    __syncthreads();

#pragma unroll
    for (int nl = half * 4; nl < half * 4 + 4; ++nl) {
        v2f acc = mk2(bb, 0.f);
#pragma unroll
        for (int c4 = 0; c4 < 8; ++c4) {
            float4 fv = *(const float4*)&ftT[nl][c4 * 4];   // broadcast read
            acc = fma2(wr2[2 * c4 + 0], mk2(fv.x, fv.y), acc);
            acc = fma2(wr2[2 * c4 + 1], mk2(fv.z, fv.w), acc);
        }
        g[(n0 + nl) * 128 + d] = acc.x + acc.y;
    }
}

// ---------------------------------------------------------------------------
// Exact KNN + fused surround branch (R5/R7-proven body). 4 queries / block.
#define CAPSEG 96
__launch_bounds__(256)
__global__ void k_knn(const float4* __restrict__ pts4, const float* __restrict__ g,
                      float* __restrict__ F) {
    __shared__ uint spillIdx[4][4][CAPSEG];   // [q][seg(=sweep wave)][slot]  6 KB
    __shared__ uint segcnt[4][4];
    __shared__ float Tsh[4];
    __shared__ uint2 selEJ[4][32];            // per query: (.x = e bits, .y = idx)

    int t = threadIdx.x, w = t >> 6, lane = t & 63;
    int qbase = blockIdx.x * 4;
    float4 qA = pts4[qbase + 0], qB = pts4[qbase + 1];
    float4 qC = pts4[qbase + 2], qD = pts4[qbase + 3];
    float4 qq = (w == 0) ? qA : (w == 1) ? qB : (w == 2) ? qC : qD;

    // packed per-query constants: d2 = fma(-2qx,px, fma(-2qy,py, fma(-2qz,pz, qw+pw)))
    v2f m2xAB = mk2(-2.f * qA.x, -2.f * qB.x), m2xCD = mk2(-2.f * qC.x, -2.f * qD.x);
    v2f m2yAB = mk2(-2.f * qA.y, -2.f * qB.y), m2yCD = mk2(-2.f * qC.y, -2.f * qD.y);
    v2f m2zAB = mk2(-2.f * qA.z, -2.f * qB.z), m2zCD = mk2(-2.f * qC.z, -2.f * qD.z);
    v2f qwAB = mk2(qA.w, qB.w), qwCD = mk2(qC.w, qD.w);
    float m2x = -2.f * qq.x, m2y = -2.f * qq.y, m2z = -2.f * qq.z, qw4 = qq.w;

    // ---- prepass: per-lane min over samples 0..2047, OWN query only ----
    float mn = 3.4e38f;
    {
        float4 pp = pts4[lane];
        for (int s = 0; s < 32; ++s) {
            float4 pnx;
            if (s < 31) pnx = pts4[lane + ((s + 1) << 6)];
            float d2 = fmaf(m2x, pp.x, fmaf(m2y, pp.y, fmaf(m2z, pp.z, qw4 + pp.w)));
            mn = fminf(mn, d2);
            pp = pnx;
        }
    }
    // exact 32nd-smallest of the 64 lane minima (bit-radix on ballots)
    {
        uint kmn = fkey(mn);
        uint P = 0x80000000u;
        for (int b = 30; b >= 0; --b) {
            uint cand = P | (1u << b);
            if ((uint)__popcll(__ballot(kmn < cand)) < 32u) P = cand;
        }
        if (lane == 0) Tsh[w] = finv(P);
    }
    __syncthreads();
    float T0 = Tsh[0], T1 = Tsh[1], T2 = Tsh[2], T3 = Tsh[3];

    // ---- sweep: wave w covers [w*2048,(w+1)*2048) for all 4 queries ----
    uint c0 = 0, c1 = 0, c2 = 0, c3 = 0;
    int cbase = (w << 11) + lane;

#define SPQ(Q, D2, TQ, CQ) { bool in_ = (D2) <= TQ; \
    u64 mk_ = __ballot(in_); \
    if (mk_) { uint pos_ = CQ + mbcnt64(mk_); \
        if (in_ && pos_ < CAPSEG) spillIdx[Q][w][pos_] = cidx; \
        CQ += (uint)__popcll(mk_); } }

    {
        float4 p = pts4[cbase];
        for (int it = 0; it < 32; ++it) {
            float4 pn;
            if (it < 31) pn = pts4[cbase + ((it + 1) << 6)];
            uint cidx = (uint)(cbase + (it << 6));
            v2f pw2 = mk2(p.w, p.w), pz2 = mk2(p.z, p.z);
            v2f py2 = mk2(p.y, p.y), px2 = mk2(p.x, p.x);
            v2f sAB = qwAB + pw2;
            sAB = fma2(m2zAB, pz2, sAB);
            sAB = fma2(m2yAB, py2, sAB);
            sAB = fma2(m2xAB, px2, sAB);
            v2f sCD = qwCD + pw2;
            sCD = fma2(m2zCD, pz2, sCD);
            sCD = fma2(m2yCD, py2, sCD);
            sCD = fma2(m2xCD, px2, sCD);
            SPQ(0, sAB.x, T0, c0)
            SPQ(1, sAB.y, T1, c1)
            SPQ(2, sCD.x, T2, c2)
            SPQ(3, sCD.y, T3, c3)
            p = pn;
        }
    }
    if (lane == 0) {
        segcnt[0][w] = c0; segcnt[1][w] = c1; segcnt[2][w] = c2; segcnt[3][w] = c3;
    }
    __syncthreads();

    // ---- refine: wave w selects exact top-32 for query qbase+w ----
    uint sA = min(segcnt[w][0], (uint)CAPSEG), sB = min(segcnt[w][1], (uint)CAPSEG);
    uint sC = min(segcnt[w][2], (uint)CAPSEG), sD = min(segcnt[w][3], (uint)CAPSEG);
    uint b1_ = sA, b2_ = sA + sB, b3_ = b2_ + sC, total = b3_ + sD;
    bool has3 = total > 192, has4 = total > 256, has5 = total > 320;

#define LOADSLOT(S, KK, ID) { \
    uint gpos = (uint)(64 * (S)) + (uint)lane; \
    KK = 0xFFFFFFFFu; ID = 0xFFFFFFFFu; \
    if (gpos < total) { \
        uint seg = (gpos >= b1_ ? 1u : 0u) + (gpos >= b2_ ? 1u : 0u) + (gpos >= b3_ ? 1u : 0u); \
        uint sub = (seg == 0u) ? 0u : (seg == 1u) ? b1_ : (seg == 2u) ? b2_ : b3_; \
        uint idx = spillIdx[w][seg][gpos - sub]; \
        float4 pz = pts4[idx]; \
        float d2 = fmaf(m2x, pz.x, fmaf(m2y, pz.y, fmaf(m2z, pz.z, qw4 + pz.w))); \
        KK = fkey(d2); ID = idx; } }

    uint kk0, kk1, kk2, kk3, kk4, kk5, id0, id1, id2, id3, id4, id5;
    LOADSLOT(0, kk0, id0)
    LOADSLOT(1, kk1, id1)
    LOADSLOT(2, kk2, id2)
    kk3 = 0xFFFFFFFFu; id3 = 0xFFFFFFFFu;
    kk4 = 0xFFFFFFFFu; id4 = 0xFFFFFFFFu;
    kk5 = 0xFFFFFFFFu; id5 = 0xFFFFFFFFu;
    if (has3) LOADSLOT(3, kk3, id3)
    if (has4) LOADSLOT(4, kk4, id4)
    if (has5) LOADSLOT(5, kk5, id5)

    // stage 1: Kc = key of 32nd-smallest spilled candidate (bit-radix, seeded)
    uint Kc = 0x80000000u;
    for (int b = 30; b >= 0; --b) {
        uint cand = Kc | (1u << b);
        uint cnt = (uint)__popcll(__ballot(kk0 < cand))
                 + (uint)__popcll(__ballot(kk1 < cand))
                 + (uint)__popcll(__ballot(kk2 < cand));
        if (has3) cnt += (uint)__popcll(__ballot(kk3 < cand));
        if (has4) cnt += (uint)__popcll(__ballot(kk4 < cand));
        if (has5) cnt += (uint)__popcll(__ballot(kk5 < cand));
        if (cnt < 32u) Kc = cand;
    }
    uint nlt = (uint)__popcll(__ballot(kk0 < Kc)) + (uint)__popcll(__ballot(kk1 < Kc))
             + (uint)__popcll(__ballot(kk2 < Kc)) + (uint)__popcll(__ballot(kk3 < Kc))
             + (uint)__popcll(__ballot(kk4 < Kc)) + (uint)__popcll(__ballot(kk5 < Kc));
    uint ntie = (uint)__popcll(__ballot(kk0 == Kc)) + (uint)__popcll(__ballot(kk1 == Kc))
              + (uint)__popcll(__ballot(kk2 == Kc)) + (uint)__popcll(__ballot(kk3 == Kc))
              + (uint)__popcll(__ballot(kk4 == Kc)) + (uint)__popcll(__ballot(kk5 == Kc));
    uint need = 32u - nlt;
    uint icut = 0xFFFFFFFFu;
    if (ntie != need) {   // tie-break by smallest index (ids unique, 13 bits)
        uint P2 = 0u;
        for (int b = 12; b >= 0; --b) {
            uint cand = P2 | (1u << b);
            uint cnt = (uint)__popcll(__ballot(kk0 == Kc && id0 < cand))
                     + (uint)__popcll(__ballot(kk1 == Kc && id1 < cand))
                     + (uint)__popcll(__ballot(kk2 == Kc && id2 < cand));
            if (has3) cnt += (uint)__popcll(__ballot(kk3 == Kc && id3 < cand));
            if (has4) cnt += (uint)__popcll(__ballot(kk4 == Kc && id4 < cand));
            if (has5) cnt += (uint)__popcll(__ballot(kk5 == Kc && id5 < cand));
            if (cnt < need) P2 = cand;
        }
        icut = P2;
    }

    // ballot-compacted write of the exact 32 selected indices into LDS
    uint dpos = 0;
#define WSEL(KK, ID) { bool acc = (KK < Kc) || (KK == Kc && ID <= icut); \
    u64 mk = __ballot(acc); \
    if (mk) { uint pos = dpos + mbcnt64(mk); \
        if (acc) selEJ[w][pos].y = ID; \
        dpos += (uint)__popcll(mk); } }
    WSEL(kk0, id0) WSEL(kk1, id1) WSEL(kk2, id2)
    WSEL(kk3, id3) WSEL(kk4, id4) WSEL(kk5, id5)

    // ---- fused surround branch (same wave, own query) ----
    int q = qbase + w;
    int k = lane & 31;
    uint j = selEJ[w][k].y;
    float4 pj = pts4[j];
    float dx = qq.x - pj.x, dy = qq.y - pj.y, dz = qq.z - pj.z;
    float dist = sqrtf(fmaf(dx, dx, fmaf(dy, dy, dz * dz)));
    float dmin = dist;
    for (int off = 16; off >= 1; off >>= 1) dmin = fminf(dmin, __shfl_xor(dmin, off));
    float e = expf(dmin - dist);
    float S = e;
    for (int off = 16; off >= 1; off >>= 1) S += __shfl_xor(S, off);
    if (lane < 32) selEJ[w][k].x = __float_as_uint(e);

    int d0 = lane * 2;
    float m0 = -INFINITY, m1 = -INFINITY;
#pragma unroll 4
    for (int kx = 0; kx < 32; ++kx) {
        uint2 ej = selEJ[w][kx];       // broadcast read
        float ek = __uint_as_float(ej.x);
        float2 gv = *(const float2*)&g[ej.y * 128u + (uint)d0];
        m0 = fmaxf(m0, ek * gv.x);
        m1 = fmaxf(m1, ek * gv.y);
    }
    float inv = 1.0f / S;
    *(float2*)&F[q * 128 + d0] = make_float2(m0 * inv, m1 * inv);
}

// ---------------------------------------------------------------------------
// out[d][n] = sum_{c<128} Wf[d][c]*F[n][c] + Wq[d]·pts[n] + bq[d]
// 16 points/block, 512 blocks (2 blocks/CU -> 8 waves/CU). Thread tile 2n x 4d.
__launch_bounds__(256)
__global__ void k_final(const float* __restrict__ F, const float* __restrict__ Wf,
                        const float* __restrict__ Wq, const float* __restrict__ bq,
                        const float4* __restrict__ pts4, float* __restrict__ out) {
    __shared__ float Fs[128 * 18];     // [k][n] padded
    __shared__ float wfs[32 * 132];    // [kk][d] padded
    int t = threadIdx.x;
    int tn = t & 7;
    int td = t >> 3;                   // 0..31
    int n0 = blockIdx.x * 16;
    int d0 = td * 4;

    {   // stage F tile via float4: 16 n x 128 k = 512 float4
        const float4* Fv = (const float4*)(F + n0 * 128);
        for (int i = t; i < 512; i += 256) {
            float4 v = Fv[i];
            int nn = i >> 5;
            int kk = (i & 31) * 4;
            Fs[(kk + 0) * 18 + nn] = v.x; Fs[(kk + 1) * 18 + nn] = v.y;
            Fs[(kk + 2) * 18 + nn] = v.z; Fs[(kk + 3) * 18 + nn] = v.w;
        }
    }

    v2f acc2[2][2];    // [n-sub][d-pair]
#pragma unroll
    for (int a = 0; a < 2; ++a)
#pragma unroll
        for (int jj = 0; jj < 2; ++jj) acc2[a][jj] = mk2(0.f, 0.f);

    for (int kc = 0; kc < 4; ++kc) {
        __syncthreads();
        for (int i = t; i < 1024; i += 256) {       // 128 d x 32 k as float4
            int d = i >> 3;
            int kkg = (i & 7) * 4;
            float4 v = *(const float4*)&Wf[d * 256 + kc * 32 + kkg];
            wfs[(kkg + 0) * 132 + d] = v.x; wfs[(kkg + 1) * 132 + d] = v.y;
            wfs[(kkg + 2) * 132 + d] = v.z; wfs[(kkg + 3) * 132 + d] = v.w;
        }
        __syncthreads();
#pragma unroll 8
        for (int kk = 0; kk < 32; ++kk) {
            int k = kc * 32 + kk;
            float2 f = *(const float2*)&Fs[k * 18 + tn * 2];
            float4 wa = *(const float4*)&wfs[kk * 132 + d0];
            v2f w0 = mk2(wa.x, wa.y), w1 = mk2(wa.z, wa.w);
            v2f fx = mk2(f.x, f.x), fy = mk2(f.y, f.y);
            acc2[0][0] = fma2(fx, w0, acc2[0][0]); acc2[1][0] = fma2(fy, w0, acc2[1][0]);
            acc2[0][1] = fma2(fx, w1, acc2[0][1]); acc2[1][1] = fma2(fy, w1, acc2[1][1]);
        }
    }

    float4 pA = pts4[n0 + tn * 2], pB = pts4[n0 + tn * 2 + 1];
#pragma unroll
    for (int jj = 0; jj < 2; ++jj) {
        int dA = d0 + 2 * jj, dB = dA + 1;
        float qa0 = Wq[dA * 3 + 0], qa1 = Wq[dA * 3 + 1], qa2 = Wq[dA * 3 + 2];
        float qb0 = Wq[dB * 3 + 0], qb1 = Wq[dB * 3 + 1], qb2 = Wq[dB * 3 + 2];
        float ba = bq[dA], bb = bq[dB];
        float oA0 = acc2[0][jj].x + fmaf(qa0, pA.x, fmaf(qa1, pA.y, fmaf(qa2, pA.z, ba)));
        float oA1 = acc2[1][jj].x + fmaf(qa0, pB.x, fmaf(qa1, pB.y, fmaf(qa2, pB.z, ba)));
        float oB0 = acc2[0][jj].y + fmaf(qb0, pA.x, fmaf(qb1, pA.y, fmaf(qb2, pA.z, bb)));
        float oB1 = acc2[1][jj].y + fmaf(qb0, pB.x, fmaf(qb1, pB.y, fmaf(qb2, pB.z, bb)));
        *(float2*)&out[dA * NPTS + n0 + tn * 2] = make_float2(oA0, oA1);
        *(float2*)&out[dB * NPTS + n0 + tn * 2] = make_float2(oB0, oB1);
    }
}

// ---------------------------------------------------------------------------
extern "C" void kernel_launch(void* const* d_in, const int* in_sizes, int n_in,
                              void* d_out, int out_size, void* d_ws, size_t ws_size,
                              hipStream_t stream) {
    const float* img_feat = (const float*)d_in[0];
    const float* cloud    = (const float*)d_in[1];
    const float* W1  = (const float*)d_in[2];
    const float* b1  = (const float*)d_in[3];
    const float* W2  = (const float*)d_in[4];
    const float* b2  = (const float*)d_in[5];
    const float* Wp1 = (const float*)d_in[6];
    const float* bp1 = (const float*)d_in[7];
    const float* Wp2 = (const float*)d_in[8];
    const float* bp2 = (const float*)d_in[9];
    const float* Wf  = (const float*)d_in[10];
    const float* bf  = (const float*)d_in[11];
    float* out = (float*)d_out;

    char* ws = (char*)d_ws;
    float4* pts4 = (float4*)(ws + OFF_PTS4);
    float* Wc  = (float*)(ws + OFF_WC);
    float* bc  = (float*)(ws + OFF_BC);
    float* Wq  = (float*)(ws + OFF_WQ);
    float* bq  = (float*)(ws + OFF_BQ);
    float* g   = (float*)(ws + OFF_G);
    float* F   = (float*)(ws + OFF_F);

    k_prep_combine<<<52, 256, 0, stream>>>(cloud, pts4, W1, b1, W2, b2,
                                           Wp1, bp1, Wp2, bp2, Wf, bf, Wc, bc, Wq, bq);
    k_gfeat<<<NPTS / 8, 256, 0, stream>>>(img_feat, Wc, bc, g);
    k_knn<<<NPTS / 4, 256, 0, stream>>>(pts4, g, F);
    k_final<<<NPTS / 32 * 2, 256, 0, stream>>>(F, Wf, Wq, bq, pts4, out);
}

// Round 10
// 76.781 us; speedup vs baseline: 1.6505x; 1.0246x over previous
//
#include <hip/hip_runtime.h>
#include <math.h>

#define NPTS 8192
#define KNN 32

typedef unsigned int uint;
typedef unsigned long long u64;
typedef float v2f __attribute__((ext_vector_type(2)));

#if __has_builtin(__builtin_elementwise_fma)
__device__ __forceinline__ v2f fma2(v2f a, v2f b, v2f c) {
    return __builtin_elementwise_fma(a, b, c);
}
#else
__device__ __forceinline__ v2f fma2(v2f a, v2f b, v2f c) {
    v2f r; r.x = fmaf(a.x, b.x, c.x); r.y = fmaf(a.y, b.y, c.y); return r;
}
#endif
__device__ __forceinline__ v2f mk2(float a, float b) { v2f r; r.x = a; r.y = b; return r; }

// ---- workspace layout (bytes) ----
#define OFF_PTS4 0                      // float4[N]            131072
#define OFF_WQ   147968                 // float[128*3]         1536  (Wf_pc@Wpc)
#define OFF_BQ   149504                 // float[128]           512   (Wf_pc@bpc+bf)
#define OFF_G    150016                 // float[N*128]         4194304
#define OFF_F    5392896                // float[N*128] row-major sur only 4194304

__device__ __forceinline__ uint fkey(float d) {
    uint bits = __float_as_uint(d);
    return bits ^ (0x80000000u | (uint)((int)bits >> 31));  // monotone sortable
}
__device__ __forceinline__ float finv(uint key) {
    uint bits = (key & 0x80000000u) ? (key ^ 0x80000000u) : ~key;
    return __uint_as_float(bits);
}
__device__ __forceinline__ uint mbcnt64(u64 m) {
    uint lo = __builtin_amdgcn_mbcnt_lo((uint)m, 0u);
    return __builtin_amdgcn_mbcnt_hi((uint)(m >> 32), lo);
}

// ---------------------------------------------------------------------------
// ONE preprocessing kernel, zero intra-kernel dependencies:
//   blocks 0..31   : pts4 = (x,y,z,|p|^2)
//   block  32      : Wq = Wf[:,128:]@(Wp2@Wp1), bq = Wf[:,128:]@(Wp2@bp1+bp2)+bf
//   blocks 33..544 : g[n][:] two-stage from raw W1/b1/W2/b2 (16 points/block)
__launch_bounds__(256)
__global__ void k_prep_gfeat(const float* __restrict__ cloud, const float* __restrict__ img_feat,
                             const float* __restrict__ W1, const float* __restrict__ b1,
                             const float* __restrict__ W2, const float* __restrict__ b2,
                             const float* __restrict__ Wp1, const float* __restrict__ bp1,
                             const float* __restrict__ Wp2, const float* __restrict__ bp2,
                             const float* __restrict__ Wf, const float* __restrict__ bf,
                             float4* __restrict__ pts4, float* __restrict__ Wq,
                             float* __restrict__ bq, float* __restrict__ g) {
    int bid = blockIdx.x;
    int t = threadIdx.x;
    if (bid < 32) {
        int n = bid * 256 + t;
        float x = cloud[n * 3 + 0], y = cloud[n * 3 + 1], z = cloud[n * 3 + 2];
        float sq = fmaf(x, x, fmaf(y, y, z * z));
        pts4[n] = make_float4(x, y, z, sq);
        return;
    }
    if (bid == 32) {
        __shared__ float wpcS[384];
        __shared__ float bpcS[128];
        for (int i = t; i < 384; i += 256) {
            int o = i / 3, c = i - o * 3;
            float a = 0.f;
            for (int u = 0; u < 64; ++u) a = fmaf(Wp2[o * 64 + u], Wp1[u * 3 + c], a);
            wpcS[i] = a;
        }
        if (t < 128) {
            float a = bp2[t];
            for (int u = 0; u < 64; ++u) a = fmaf(Wp2[t * 64 + u], bp1[u], a);
            bpcS[t] = a;
        }
        __syncthreads();
        for (int i = t; i < 384; i += 256) {
            int d = i / 3, c = i - d * 3;
            float a = 0.f;
            for (int o = 0; o < 128; ++o) a = fmaf(Wf[d * 256 + 128 + o], wpcS[o * 3 + c], a);
            Wq[i] = a;
        }
        if (t < 128) {
            float a = bf[t];
            for (int o = 0; o < 128; ++o) a = fmaf(Wf[t * 256 + 128 + o], bpcS[o], a);
            bq[t] = a;
        }
        return;
    }
    // ---- gfeat: 16 points, two-stage (no precomputed Wc needed) ----
    {
        __shared__ float ftT[16][36];   // [n][c]
        __shared__ float hS[16][68];    // [n][o]
        int n0 = (bid - 33) * 16;

        if (t < 128) {                  // 32c x 16n, one float4 per thread
            int c = t >> 2, ng = (t & 3) * 4;
            float4 v = *(const float4*)&img_feat[c * NPTS + n0 + ng];
            ftT[ng + 0][c] = v.x; ftT[ng + 1][c] = v.y;
            ftT[ng + 2][c] = v.z; ftT[ng + 3][c] = v.w;
        }
        __syncthreads();

        // stage 1: h[n][o] = b1[o] + sum_c W1[o][c] * ft[n][c]
        {
            int n = t & 15, ob = t >> 4;           // ob in 0..15
            v2f fr[16];
#pragma unroll
            for (int c4 = 0; c4 < 8; ++c4) {
                float4 fv = *(const float4*)&ftT[n][c4 * 4];
                fr[2 * c4 + 0] = mk2(fv.x, fv.y);
                fr[2 * c4 + 1] = mk2(fv.z, fv.w);
            }
#pragma unroll
            for (int r = 0; r < 4; ++r) {
                int o = ob + r * 16;
                v2f acc = mk2(b1[o], 0.f);
                const float4* w1r = (const float4*)&W1[o * 32];
#pragma unroll
                for (int c4 = 0; c4 < 8; ++c4) {
                    float4 wv = w1r[c4];
                    acc = fma2(mk2(wv.x, wv.y), fr[2 * c4 + 0], acc);
                    acc = fma2(mk2(wv.z, wv.w), fr[2 * c4 + 1], acc);
                }
                hS[n][o] = acc.x + acc.y;
            }
        }
        __syncthreads();

        // stage 2: g[n][d] = b2[d] + sum_o W2[d][o] * h[n][o]
        {
            int d = t & 127, grp = t >> 7;
            v2f w2r[32];
#pragma unroll
            for (int o4 = 0; o4 < 16; ++o4) {
                float4 wv = *(const float4*)&W2[d * 64 + o4 * 4];
                w2r[2 * o4 + 0] = mk2(wv.x, wv.y);
                w2r[2 * o4 + 1] = mk2(wv.z, wv.w);
            }
            float b2d = b2[d];
#pragma unroll
            for (int nl = grp * 8; nl < grp * 8 + 8; ++nl) {
                v2f acc = mk2(b2d, 0.f);
#pragma unroll
                for (int o4 = 0; o4 < 16; ++o4) {
                    float4 hv = *(const float4*)&hS[nl][o4 * 4];   // broadcast
                    acc = fma2(w2r[2 * o4 + 0], mk2(hv.x, hv.y), acc);
                    acc = fma2(w2r[2 * o4 + 1], mk2(hv.z, hv.w), acc);
                }
                g[(n0 + nl) * 128 + d] = acc.x + acc.y;
            }
        }
    }
}

// ---------------------------------------------------------------------------
// Exact KNN + fused surround branch (R5/R7/R9-proven body, byte-identical).
#define CAPSEG 96
__launch_bounds__(256)
__global__ void k_knn(const float4* __restrict__ pts4, const float* __restrict__ g,
                      float* __restrict__ F) {
    __shared__ uint spillIdx[4][4][CAPSEG];   // [q][seg(=sweep wave)][slot]  6 KB
    __shared__ uint segcnt[4][4];
    __shared__ float Tsh[4];
    __shared__ uint2 selEJ[4][32];            // per query: (.x = e bits, .y = idx)

    int t = threadIdx.x, w = t >> 6, lane = t & 63;
    int qbase = blockIdx.x * 4;
    float4 qA = pts4[qbase + 0], qB = pts4[qbase + 1];
    float4 qC = pts4[qbase + 2], qD = pts4[qbase + 3];
    float4 qq = (w == 0) ? qA : (w == 1) ? qB : (w == 2) ? qC : qD;

    // packed per-query constants: d2 = fma(-2qx,px, fma(-2qy,py, fma(-2qz,pz, qw+pw)))
    v2f m2xAB = mk2(-2.f * qA.x, -2.f * qB.x), m2xCD = mk2(-2.f * qC.x, -2.f * qD.x);
    v2f m2yAB = mk2(-2.f * qA.y, -2.f * qB.y), m2yCD = mk2(-2.f * qC.y, -2.f * qD.y);
    v2f m2zAB = mk2(-2.f * qA.z, -2.f * qB.z), m2zCD = mk2(-2.f * qC.z, -2.f * qD.z);
    v2f qwAB = mk2(qA.w, qB.w), qwCD = mk2(qC.w, qD.w);
    float m2x = -2.f * qq.x, m2y = -2.f * qq.y, m2z = -2.f * qq.z, qw4 = qq.w;

    // ---- prepass: per-lane min over samples 0..2047, OWN query only ----
    float mn = 3.4e38f;
    {
        float4 pp = pts4[lane];
        for (int s = 0; s < 32; ++s) {
            float4 pnx;
            if (s < 31) pnx = pts4[lane + ((s + 1) << 6)];
            float d2 = fmaf(m2x, pp.x, fmaf(m2y, pp.y, fmaf(m2z, pp.z, qw4 + pp.w)));
            mn = fminf(mn, d2);
            pp = pnx;
        }
    }
    // exact 32nd-smallest of the 64 lane minima (bit-radix on ballots)
    {
        uint kmn = fkey(mn);
        uint P = 0x80000000u;
        for (int b = 30; b >= 0; --b) {
            uint cand = P | (1u << b);
            if ((uint)__popcll(__ballot(kmn < cand)) < 32u) P = cand;
        }
        if (lane == 0) Tsh[w] = finv(P);
    }
    __syncthreads();
    float T0 = Tsh[0], T1 = Tsh[1], T2 = Tsh[2], T3 = Tsh[3];

    // ---- sweep: wave w covers [w*2048,(w+1)*2048) for all 4 queries ----
    uint c0 = 0, c1 = 0, c2 = 0, c3 = 0;
    int cbase = (w << 11) + lane;

#define SPQ(Q, D2, TQ, CQ) { bool in_ = (D2) <= TQ; \
    u64 mk_ = __ballot(in_); \
    if (mk_) { uint pos_ = CQ + mbcnt64(mk_); \
        if (in_ && pos_ < CAPSEG) spillIdx[Q][w][pos_] = cidx; \
        CQ += (uint)__popcll(mk_); } }

    {
        float4 p = pts4[cbase];
        for (int it = 0; it < 32; ++it) {
            float4 pn;
            if (it < 31) pn = pts4[cbase + ((it + 1) << 6)];
            uint cidx = (uint)(cbase + (it << 6));
            v2f pw2 = mk2(p.w, p.w), pz2 = mk2(p.z, p.z);
            v2f py2 = mk2(p.y, p.y), px2 = mk2(p.x, p.x);
            v2f sAB = qwAB + pw2;
            sAB = fma2(m2zAB, pz2, sAB);
            sAB = fma2(m2yAB, py2, sAB);
            sAB = fma2(m2xAB, px2, sAB);
            v2f sCD = qwCD + pw2;
            sCD = fma2(m2zCD, pz2, sCD);
            sCD = fma2(m2yCD, py2, sCD);
            sCD = fma2(m2xCD, px2, sCD);
            SPQ(0, sAB.x, T0, c0)
            SPQ(1, sAB.y, T1, c1)
            SPQ(2, sCD.x, T2, c2)
            SPQ(3, sCD.y, T3, c3)
            p = pn;
        }
    }
    if (lane == 0) {
        segcnt[0][w] = c0; segcnt[1][w] = c1; segcnt[2][w] = c2; segcnt[3][w] = c3;
    }
    __syncthreads();

    // ---- refine: wave w selects exact top-32 for query qbase+w ----
    uint sA = min(segcnt[w][0], (uint)CAPSEG), sB = min(segcnt[w][1], (uint)CAPSEG);
    uint sC = min(segcnt[w][2], (uint)CAPSEG), sD = min(segcnt[w][3], (uint)CAPSEG);
    uint b1_ = sA, b2_ = sA + sB, b3_ = b2_ + sC, total = b3_ + sD;
    bool has3 = total > 192, has4 = total > 256, has5 = total > 320;

#define LOADSLOT(S, KK, ID) { \
    uint gpos = (uint)(64 * (S)) + (uint)lane; \
    KK = 0xFFFFFFFFu; ID = 0xFFFFFFFFu; \
    if (gpos < total) { \
        uint seg = (gpos >= b1_ ? 1u : 0u) + (gpos >= b2_ ? 1u : 0u) + (gpos >= b3_ ? 1u : 0u); \
        uint sub = (seg == 0u) ? 0u : (seg == 1u) ? b1_ : (seg == 2u) ? b2_ : b3_; \
        uint idx = spillIdx[w][seg][gpos - sub]; \
        float4 pz = pts4[idx]; \
        float d2 = fmaf(m2x, pz.x, fmaf(m2y, pz.y, fmaf(m2z, pz.z, qw4 + pz.w))); \
        KK = fkey(d2); ID = idx; } }

    uint kk0, kk1, kk2, kk3, kk4, kk5, id0, id1, id2, id3, id4, id5;
    LOADSLOT(0, kk0, id0)
    LOADSLOT(1, kk1, id1)
    LOADSLOT(2, kk2, id2)
    kk3 = 0xFFFFFFFFu; id3 = 0xFFFFFFFFu;
    kk4 = 0xFFFFFFFFu; id4 = 0xFFFFFFFFu;
    kk5 = 0xFFFFFFFFu; id5 = 0xFFFFFFFFu;
    if (has3) LOADSLOT(3, kk3, id3)
    if (has4) LOADSLOT(4, kk4, id4)
    if (has5) LOADSLOT(5, kk5, id5)

    // stage 1: Kc = key of 32nd-smallest spilled candidate (bit-radix, seeded)
    uint Kc = 0x80000000u;
    for (int b = 30; b >= 0; --b) {
        uint cand = Kc | (1u << b);
        uint cnt = (uint)__popcll(__ballot(kk0 < cand))
                 + (uint)__popcll(__ballot(kk1 < cand))
                 + (uint)__popcll(__ballot(kk2 < cand));
        if (has3) cnt += (uint)__popcll(__ballot(kk3 < cand));
        if (has4) cnt += (uint)__popcll(__ballot(kk4 < cand));
        if (has5) cnt += (uint)__popcll(__ballot(kk5 < cand));
        if (cnt < 32u) Kc = cand;
    }
    uint nlt = (uint)__popcll(__ballot(kk0 < Kc)) + (uint)__popcll(__ballot(kk1 < Kc))
             + (uint)__popcll(__ballot(kk2 < Kc)) + (uint)__popcll(__ballot(kk3 < Kc))
             + (uint)__popcll(__ballot(kk4 < Kc)) + (uint)__popcll(__ballot(kk5 < Kc));
    uint ntie = (uint)__popcll(__ballot(kk0 == Kc)) + (uint)__popcll(__ballot(kk1 == Kc))
              + (uint)__popcll(__ballot(kk2 == Kc)) + (uint)__popcll(__ballot(kk3 == Kc))
              + (uint)__popcll(__ballot(kk4 == Kc)) + (uint)__popcll(__ballot(kk5 == Kc));
    uint need = 32u - nlt;
    uint icut = 0xFFFFFFFFu;
    if (ntie != need) {   // tie-break by smallest index (ids unique, 13 bits)
        uint P2 = 0u;
        for (int b = 12; b >= 0; --b) {
            uint cand = P2 | (1u << b);
            uint cnt = (uint)__popcll(__ballot(kk0 == Kc && id0 < cand))
                     + (uint)__popcll(__ballot(kk1 == Kc && id1 < cand))
                     + (uint)__popcll(__ballot(kk2 == Kc && id2 < cand));
            if (has3) cnt += (uint)__popcll(__ballot(kk3 == Kc && id3 < cand));
            if (has4) cnt += (uint)__popcll(__ballot(kk4 == Kc && id4 < cand));
            if (has5) cnt += (uint)__popcll(__ballot(kk5 == Kc && id5 < cand));
            if (cnt < need) P2 = cand;
        }
        icut = P2;
    }

    // ballot-compacted write of the exact 32 selected indices into LDS
    uint dpos = 0;
#define WSEL(KK, ID) { bool acc = (KK < Kc) || (KK == Kc && ID <= icut); \
    u64 mk = __ballot(acc); \
    if (mk) { uint pos = dpos + mbcnt64(mk); \
        if (acc) selEJ[w][pos].y = ID; \
        dpos += (uint)__popcll(mk); } }
    WSEL(kk0, id0) WSEL(kk1, id1) WSEL(kk2, id2)
    WSEL(kk3, id3) WSEL(kk4, id4) WSEL(kk5, id5)

    // ---- fused surround branch (same wave, own query) ----
    int q = qbase + w;
    int k = lane & 31;
    uint j = selEJ[w][k].y;
    float4 pj = pts4[j];
    float dx = qq.x - pj.x, dy = qq.y - pj.y, dz = qq.z - pj.z;
    float dist = sqrtf(fmaf(dx, dx, fmaf(dy, dy, dz * dz)));
    float dmin = dist;
    for (int off = 16; off >= 1; off >>= 1) dmin = fminf(dmin, __shfl_xor(dmin, off));
    float e = expf(dmin - dist);
    float S = e;
    for (int off = 16; off >= 1; off >>= 1) S += __shfl_xor(S, off);
    if (lane < 32) selEJ[w][k].x = __float_as_uint(e);

    int d0 = lane * 2;
    float m0 = -INFINITY, m1 = -INFINITY;
#pragma unroll 4
    for (int kx = 0; kx < 32; ++kx) {
        uint2 ej = selEJ[w][kx];       // broadcast read
        float ek = __uint_as_float(ej.x);
        float2 gv = *(const float2*)&g[ej.y * 128u + (uint)d0];
        m0 = fmaxf(m0, ek * gv.x);
        m1 = fmaxf(m1, ek * gv.y);
    }
    float inv = 1.0f / S;
    *(float2*)&F[q * 128 + d0] = make_float2(m0 * inv, m1 * inv);
}

// ---------------------------------------------------------------------------
// out[d][n] = sum_{c<128} Wf[d][c]*F[n][c] + Wq[d]·pts[n] + bq[d]
// 16 points/block, 512 blocks (2 blocks/CU -> 8 waves/CU). Thread tile 2n x 4d.
__launch_bounds__(256)
__global__ void k_final(const float* __restrict__ F, const float* __restrict__ Wf,
                        const float* __restrict__ Wq, const float* __restrict__ bq,
                        const float4* __restrict__ pts4, float* __restrict__ out) {
    __shared__ float Fs[128 * 18];     // [k][n] padded
    __shared__ float wfs[32 * 132];    // [kk][d] padded
    int t = threadIdx.x;
    int tn = t & 7;
    int td = t >> 3;                   // 0..31
    int n0 = blockIdx.x * 16;
    int d0 = td * 4;

    {   // stage F tile via float4: 16 n x 128 k = 512 float4
        const float4* Fv = (const float4*)(F + n0 * 128);
        for (int i = t; i < 512; i += 256) {
            float4 v = Fv[i];
            int nn = i >> 5;
            int kk = (i & 31) * 4;
            Fs[(kk + 0) * 18 + nn] = v.x; Fs[(kk + 1) * 18 + nn] = v.y;
            Fs[(kk + 2) * 18 + nn] = v.z; Fs[(kk + 3) * 18 + nn] = v.w;
        }
    }

    v2f acc2[2][2];    // [n-sub][d-pair]
#pragma unroll
    for (int a = 0; a < 2; ++a)
#pragma unroll
        for (int jj = 0; jj < 2; ++jj) acc2[a][jj] = mk2(0.f, 0.f);

    for (int kc = 0; kc < 4; ++kc) {
        __syncthreads();
        for (int i = t; i < 1024; i += 256) {       // 128 d x 32 k as float4
            int d = i >> 3;
            int kkg = (i & 7) * 4;
            float4 v = *(const float4*)&Wf[d * 256 + kc * 32 + kkg];
            wfs[(kkg + 0) * 132 + d] = v.x; wfs[(kkg + 1) * 132 + d] = v.y;
            wfs[(kkg + 2) * 132 + d] = v.z; wfs[(kkg + 3) * 132 + d] = v.w;
        }
        __syncthreads();
#pragma unroll 8
        for (int kk = 0; kk < 32; ++kk) {
            int k = kc * 32 + kk;
            float2 f = *(const float2*)&Fs[k * 18 + tn * 2];
            float4 wa = *(const float4*)&wfs[kk * 132 + d0];
            v2f w0 = mk2(wa.x, wa.y), w1 = mk2(wa.z, wa.w);
            v2f fx = mk2(f.x, f.x), fy = mk2(f.y, f.y);
            acc2[0][0] = fma2(fx, w0, acc2[0][0]); acc2[1][0] = fma2(fy, w0, acc2[1][0]);
            acc2[0][1] = fma2(fx, w1, acc2[0][1]); acc2[1][1] = fma2(fy, w1, acc2[1][1]);
        }
    }

    float4 pA = pts4[n0 + tn * 2], pB = pts4[n0 + tn * 2 + 1];
#pragma unroll
    for (int jj = 0; jj < 2; ++jj) {
        int dA = d0 + 2 * jj, dB = dA + 1;
        float qa0 = Wq[dA * 3 + 0], qa1 = Wq[dA * 3 + 1], qa2 = Wq[dA * 3 + 2];
        float qb0 = Wq[dB * 3 + 0], qb1 = Wq[dB * 3 + 1], qb2 = Wq[dB * 3 + 2];
        float ba = bq[dA], bb = bq[dB];
        float oA0 = acc2[0][jj].x + fmaf(qa0, pA.x, fmaf(qa1, pA.y, fmaf(qa2, pA.z, ba)));
        float oA1 = acc2[1][jj].x + fmaf(qa0, pB.x, fmaf(qa1, pB.y, fmaf(qa2, pB.z, ba)));
        float oB0 = acc2[0][jj].y + fmaf(qb0, pA.x, fmaf(qb1, pA.y, fmaf(qb2, pA.z, bb)));
        float oB1 = acc2[1][jj].y + fmaf(qb0, pB.x, fmaf(qb1, pB.y, fmaf(qb2, pB.z, bb)));
        *(float2*)&out[dA * NPTS + n0 + tn * 2] = make_float2(oA0, oA1);
        *(float2*)&out[dB * NPTS + n0 + tn * 2] = make_float2(oB0, oB1);
    }
}

// ---------------------------------------------------------------------------
extern "C" void kernel_launch(void* const* d_in, const int* in_sizes, int n_in,
                              void* d_out, int out_size, void* d_ws, size_t ws_size,
                              hipStream_t stream) {
    const float* img_feat = (const float*)d_in[0];
    const float* cloud    = (const float*)d_in[1];
    const float* W1  = (const float*)d_in[2];
    const float* b1  = (const float*)d_in[3];
    const float* W2  = (const float*)d_in[4];
    const float* b2  = (const float*)d_in[5];
    const float* Wp1 = (const float*)d_in[6];
    const float* bp1 = (const float*)d_in[7];
    const float* Wp2 = (const float*)d_in[8];
    const float* bp2 = (const float*)d_in[9];
    const float* Wf  = (const float*)d_in[10];
    const float* bf  = (const float*)d_in[11];
    float* out = (float*)d_out;

    char* ws = (char*)d_ws;
    float4* pts4 = (float4*)(ws + OFF_PTS4);
    float* Wq  = (float*)(ws + OFF_WQ);
    float* bq  = (float*)(ws + OFF_BQ);
    float* g   = (float*)(ws + OFF_G);
    float* F   = (float*)(ws + OFF_F);

    k_prep_gfeat<<<545, 256, 0, stream>>>(cloud, img_feat, W1, b1, W2, b2,
                                          Wp1, bp1, Wp2, bp2, Wf, bf,
                                          pts4, Wq, bq, g);
    k_knn<<<NPTS / 4, 256, 0, stream>>>(pts4, g, F);
    k_final<<<NPTS / 32 * 2, 256, 0, stream>>>(F, Wf, Wq, bq, pts4, out);
}